// Round 9
// baseline (394.391 us; speedup 1.0000x reference)
//
#include <hip/hip_runtime.h>
#include <hip/hip_bf16.h>
#include <math.h>

// ---- problem constants ----
#define S_LEN   2048
#define HIDN    1024
#define NHEADS  16
#define HDIM    64
#define NTOK    4096   // B*S
#define DFFN    4096

#define LOG2E 1.44269504088896f

typedef __attribute__((ext_vector_type(8))) __bf16 bf16x8;
typedef __attribute__((ext_vector_type(4))) float  f32x4;

static __device__ __forceinline__ ushort f2bf(float f) {
  union { float f; unsigned u; } v; v.f = f;
  unsigned u = v.u;
  unsigned r = (u + 0x7fffu + ((u >> 16) & 1u)) >> 16;  // RNE
  return (ushort)r;
}

// async global->LDS, 16B per lane; LDS dest = wave-uniform base + lane*16 (HW-appended)
#define GLOAD16(gp, lp)                                                              \
  __builtin_amdgcn_global_load_lds((const __attribute__((address_space(1))) void*)(gp), \
                                   (__attribute__((address_space(3))) void*)(lp), 16, 0, 0)

// ---------------- fused transpose-convert: all weights fp32 [K][N] -> bf16 [N][K] ----------------
__global__ __launch_bounds__(256) void convert_all(const float* __restrict__ Wq,
                                                   const float* __restrict__ Wk,
                                                   const float* __restrict__ Wv,
                                                   const float* __restrict__ Wo,
                                                   const float* __restrict__ W1,
                                                   const float* __restrict__ W2,
                                                   ushort* __restrict__ wqkvT,
                                                   ushort* __restrict__ woT,
                                                   ushort* __restrict__ w1T,
                                                   ushort* __restrict__ w2T) {
  __shared__ float tile[32][33];
  int id = blockIdx.x;
  const float* W; ushort* WT; int K, N, tl;
  if (id < 3072) {                 // Wq/Wk/Wv: 1024x1024 each
    int i = id >> 10; tl = id & 1023;
    W = (i == 0) ? Wq : (i == 1) ? Wk : Wv;
    WT = wqkvT + i * 1024 * 1024; K = 1024; N = 1024;
  } else if (id < 4096) { tl = id - 3072; W = Wo; WT = woT; K = 1024; N = 1024; }
  else if (id < 8192)   { tl = id - 4096; W = W1; WT = w1T; K = 1024; N = 4096; }
  else                  { tl = id - 8192; W = W2; WT = w2T; K = 4096; N = 1024; }
  int ntn = N >> 5;
  int n0 = (tl % ntn) * 32, k0 = (tl / ntn) * 32;
  int tx = threadIdx.x & 31, ty = threadIdx.x >> 5;  // ty 0..7
#pragma unroll
  for (int i = 0; i < 4; i++)
    tile[ty + i * 8][tx] = W[(size_t)(k0 + ty + i * 8) * N + n0 + tx];
  __syncthreads();
#pragma unroll
  for (int i = 0; i < 4; i++)
    WT[(size_t)(n0 + ty + i * 8) * K + k0 + tx] = f2bf(tile[tx][ty + i * 8]);
}

// ---------------- RMSNorm: fp32 row -> bf16 row ----------------
__global__ __launch_bounds__(256) void rmsnorm_kernel(const float* __restrict__ x,
                                                      const float* __restrict__ w,
                                                      ushort* __restrict__ out) {
  int row = blockIdx.x, t = threadIdx.x;
  const float4* x4 = (const float4*)(x + (size_t)row * HIDN);
  float4 v = x4[t];
  float ss = v.x * v.x + v.y * v.y + v.z * v.z + v.w * v.w;
#pragma unroll
  for (int m = 32; m; m >>= 1) ss += __shfl_xor(ss, m, 64);
  __shared__ float wsum[4];
  if ((t & 63) == 0) wsum[t >> 6] = ss;
  __syncthreads();
  float tot = wsum[0] + wsum[1] + wsum[2] + wsum[3];
  float rs = rsqrtf(tot * (1.0f / HIDN) + 1e-6f);
  const float4* w4 = (const float4*)w;
  float4 wv = w4[t];
  ushort4 o;
  o.x = f2bf(v.x * rs * wv.x);
  o.y = f2bf(v.y * rs * wv.y);
  o.z = f2bf(v.z * rs * wv.z);
  o.w = f2bf(v.w * rs * wv.w);
  *(ushort4*)(out + (size_t)row * HIDN + t * 4) = o;
}

// ---------------- out = x2 + 0.5*b2 (seed for split-K FFN2 atomics) ----------------
__global__ __launch_bounds__(256) void out_init(const float* __restrict__ x2,
                                                const float* __restrict__ b2,
                                                float* __restrict__ out) {
  int i = blockIdx.x * 256 + threadIdx.x;        // over 1M float4
  float4 xv = ((const float4*)x2)[i];
  float4 bv = ((const float4*)b2)[i & 255];      // 256 float4 per row of 1024
  float4 o = {xv.x + 0.5f * bv.x, xv.y + 0.5f * bv.y,
              xv.z + 0.5f * bv.z, xv.w + 0.5f * bv.w};
  ((float4*)out)[i] = o;
}

// ---------------- bf16 MFMA GEMM, A[M][K] x B^T[N][K], TMx128 tile, BK=64 ----------------
// XCD-aware block swizzle (all grids have nwg % 8 == 0).
// EPI: 0 = QKV scatter (bias = bq, resid = bk; q*0.125*log2e, V transposed),
//      1 = Wo (+resid -> fp32), 2 = W1 (+bias, gelu -> bf16), 3 = W2 (resid + 0.5*(acc+bias)),
//      5 = W2 split-K: atomicAdd 0.5*acc into pre-seeded out (blockIdx.z = K half)
template <int EPI, int TM>
__global__ __launch_bounds__(256, TM == 128 ? 3 : 4)
void gemm_bt(const ushort* __restrict__ A,
             const ushort* __restrict__ B,
             int M, int N, int K,
             const float* __restrict__ bias,
             const float* __restrict__ resid,
             float* __restrict__ outf,
             ushort* __restrict__ outb,
             ushort* __restrict__ qb,
             ushort* __restrict__ kb,
             ushort* __restrict__ vb) {
  constexpr int NF = (TM == 128) ? 4 : 2;    // 16-col fragments per wave
  __shared__ __align__(16) ushort As[TM * 64];
  __shared__ __align__(16) ushort Bs[128 * 64];
  int t = threadIdx.x;
  int w = t >> 6, l = t & 63;
  int wmr = (TM == 128) ? (w >> 1) * 64 : 0;        // wave row base
  int wnc = (TM == 128) ? (w & 1) * 64 : w * 32;    // wave col base
  int lr = l & 15, lg = l >> 4;

  // XCD swizzle (x,y only; z = split-K slice)
  int nwg = gridDim.x * gridDim.y;
  int bid = blockIdx.y * gridDim.x + blockIdx.x;
  int swz = (bid & 7) * (nwg >> 3) + (bid >> 3);
  int bx = swz % gridDim.x, by = swz / gridDim.x;
  int m0 = bx * TM, n0 = by * 128;

  int klen = (EPI == 5) ? (K >> 1) : K;
  int kbeg = (EPI == 5) ? blockIdx.z * klen : 0;

  // staging: each GLOAD16 covers 8 rows x 64 cols; lane l -> row l>>3,
  // LDS granule l&7, sourced from global granule (l&7)^(l>>3)  [swizzle]
  int srl = l >> 3;
  int sg  = ((l & 7) ^ srl) * 8;
  const ushort* Ag = A + (size_t)(m0 + w * (TM / 4) + srl) * K + sg;
  const ushort* Bg = B + (size_t)(n0 + w * 32 + srl) * K + sg;
  ushort* Asw = &As[(w * (TM / 4)) * 64];
  ushort* Bsw = &Bs[(w * 32) * 64];

  f32x4 acc[4][NF] = {};

  for (int k0 = kbeg; k0 < kbeg + klen; k0 += 64) {
#pragma unroll
    for (int c = 0; c < TM / 32; c++)
      GLOAD16(Ag + (size_t)(8 * c) * K + k0, Asw + (8 * c) * 64);
#pragma unroll
    for (int c = 0; c < 4; c++)
      GLOAD16(Bg + (size_t)(8 * c) * K + k0, Bsw + (8 * c) * 64);
    __syncthreads();  // drains vmcnt -> LDS tiles ready

    bf16x8 af[4][2], bfr[NF][2];
#pragma unroll
    for (int mf = 0; mf < 4; mf++)
#pragma unroll
      for (int ks = 0; ks < 2; ks++)
        af[mf][ks] = *(const bf16x8*)(&As[(wmr + mf * 16 + lr) * 64 +
                                          (((ks * 4 + lg) ^ (lr & 7)) << 3)]);
#pragma unroll
    for (int nf = 0; nf < NF; nf++)
#pragma unroll
      for (int ks = 0; ks < 2; ks++)
        bfr[nf][ks] = *(const bf16x8*)(&Bs[(wnc + nf * 16 + lr) * 64 +
                                           (((ks * 4 + lg) ^ (lr & 7)) << 3)]);
#pragma unroll
    for (int mf = 0; mf < 4; mf++)
#pragma unroll
      for (int nf = 0; nf < NF; nf++) {
        acc[mf][nf] = __builtin_amdgcn_mfma_f32_16x16x32_bf16(af[mf][0], bfr[nf][0], acc[mf][nf], 0, 0, 0);
        acc[mf][nf] = __builtin_amdgcn_mfma_f32_16x16x32_bf16(af[mf][1], bfr[nf][1], acc[mf][nf], 0, 0, 0);
      }
    __syncthreads();  // all reads done before next overwrite
  }

  // epilogue: C row = (l>>4)*4 + r, col = l&15  [verified C/D layout]
  int lg4 = lg * 4;
  if constexpr (EPI == 0) {
#pragma unroll
    for (int mf = 0; mf < 4; mf++) {
      int row0 = m0 + wmr + mf * 16 + lg4;
      int bb = row0 >> 11, ss0 = row0 & 2047;
#pragma unroll
      for (int nf = 0; nf < NF; nf++) {
        int col = n0 + wnc + nf * 16 + lr;
        int which = col >> 10, nn = col & 1023;
        int hh = nn >> 6, dd = nn & 63;
        float bcol = (which == 0) ? bias[nn] : (which == 1) ? resid[nn] : 0.0f;
        if (which == 2) {
          // V transposed: vT[bh][d][s]; 4 consecutive ss pack into ushort4
          ushort4 o;
          o.x = f2bf(acc[mf][nf][0]);
          o.y = f2bf(acc[mf][nf][1]);
          o.z = f2bf(acc[mf][nf][2]);
          o.w = f2bf(acc[mf][nf][3]);
          *(ushort4*)(vb + ((size_t)(bb * NHEADS + hh) * HDIM + dd) * S_LEN + ss0) = o;
        } else {
#pragma unroll
          for (int r = 0; r < 4; r++) {
            float v = acc[mf][nf][r] + bcol;
            size_t idx = ((size_t)(bb * NHEADS + hh) * S_LEN + ss0 + r) * HDIM + dd;
            if (which == 0) qb[idx] = f2bf(v * (0.125f * LOG2E));
            else kb[idx] = f2bf(v);
          }
        }
      }
    }
  } else {
#pragma unroll
    for (int mf = 0; mf < 4; mf++) {
#pragma unroll
      for (int nf = 0; nf < NF; nf++) {
#pragma unroll
        for (int r = 0; r < 4; r++) {
          int row = m0 + wmr + mf * 16 + lg4 + r;
          int col = n0 + wnc + nf * 16 + lr;
          float v = acc[mf][nf][r];
          if constexpr (EPI == 1) {
            outf[(size_t)row * HIDN + col] = resid[(size_t)row * HIDN + col] + v;
          } else if constexpr (EPI == 2) {
            float tv = v + bias[col];
            float gl = 0.5f * tv * (1.0f + erff(tv * 0.70710678118f));
            outb[(size_t)row * DFFN + col] = f2bf(gl);
          } else if constexpr (EPI == 3) {
            outf[(size_t)row * HIDN + col] =
                resid[(size_t)row * HIDN + col] + 0.5f * (v + bias[col]);
          } else {  // EPI == 5: split-K accumulate (out pre-seeded with x2 + 0.5*b2)
            unsafeAtomicAdd(&outf[(size_t)row * HIDN + col], 0.5f * v);
          }
        }
      }
    }
  }
}

// ---------------- flash attention with ALiBi — lane-local P + dead-tile skip ----------------
// Block mapping: XCD x gets 128 blocks covering head-pair {hp, hp+8} (K/V 2MB, L2-fits);
// each CU hosts 2 low-h + 2 high-h blocks -> ALiBi tile-skip is load-balanced.
// Skip: P = exp2(S-m) < 2^-25 contributes nothing (data-driven, mrow only grows).
__global__ __launch_bounds__(256, 4) void attn_kernel(const ushort* __restrict__ qb,
                                                      const ushort* __restrict__ kb,
                                                      const ushort* __restrict__ vt,
                                                      ushort* __restrict__ attn_out) {
  __shared__ __align__(16) ushort Ks[2][64 * 64];
  __shared__ __align__(16) ushort VTs[2][64 * 64];
  int t = threadIdx.x;
  int w = t >> 6, l = t & 63;
  int lr = l & 15, lg = l >> 4, g8 = lg * 8;

  // head-pair XCD mapping: v = xcd*128 + idx; qt = v&31; g = v>>5;
  // hs = g&1, bhp = g>>1; b = bhp>>3, hp = bhp&7; h = hp + 8*hs
  int bid = blockIdx.x;
  int v = (bid & 7) * 128 + (bid >> 3);
  int qt = v & 31;
  int g = v >> 5;
  int h = (g >> 1 & 7) + 8 * (g & 1);
  int bh = (g >> 4) * 16 + h;
  float slope2 = exp2f(-0.5f * (float)(h + 1)) * LOG2E;  // log2-domain alibi slope
  float s64v = slope2 * 64.0f;
  int q0 = qt * 64;
  const ushort* qp = qb + (size_t)bh * S_LEN * HDIM;
  const ushort* kp = kb + (size_t)bh * S_LEN * HDIM;
  const ushort* vp = vt + (size_t)bh * HDIM * S_LEN;

  // staging: chunk c covers rows w*16+8c..+7; source granule = (l&7) ^ S(row),
  // S(row) = (row&3) | ((row>>3)&1)<<2; row = w*16+8c+(l>>3) -> S = ((l>>3)&3) | (c<<2)
  int S0 = (l >> 3) & 3;
  size_t kof0 = (size_t)(w * 16 + (l >> 3)) * HDIM + (size_t)(((l & 7) ^ S0) * 8);
  size_t kof1 = (size_t)(w * 16 + 8 + (l >> 3)) * HDIM + (size_t)(((l & 7) ^ S0 ^ 4) * 8);
  size_t vof0 = (size_t)(w * 16 + (l >> 3)) * S_LEN + (size_t)(((l & 7) ^ S0) * 8);
  size_t vof1 = (size_t)(w * 16 + 8 + (l >> 3)) * S_LEN + (size_t)(((l & 7) ^ S0 ^ 4) * 8);

  auto stage = [&](int tile, int b) {
    const ushort* ks_ = kp + (size_t)tile * 64 * HDIM;
    const ushort* vs_ = vp + tile * 64;
    GLOAD16(ks_ + kof0, &Ks[b][(w * 16) * 64]);
    GLOAD16(ks_ + kof1, &Ks[b][(w * 16 + 8) * 64]);
    GLOAD16(vs_ + vof0, &VTs[b][(w * 16) * 64]);
    GLOAD16(vs_ + vof1, &VTs[b][(w * 16 + 8) * 64]);
  };

  // Q as B-frag: B[col=lr][k]
  bf16x8 qf[2];
#pragma unroll
  for (int ks = 0; ks < 2; ks++)
    qf[ks] = *(const bf16x8*)(qp + (size_t)(q0 + w * 16 + lr) * HDIM + ks * 32 + g8);

  f32x4 ao[4] = {};                 // O[q = lg*4+r][d = nf*16+lr]
  float mrow = -INFINITY, lden = 0.f;  // per-thread: one q-row (q = w*16+lr)

  // lane-local kv coords of sc[nf][r]: kvloc = 32*(nf>>1) + 8*lg + 4*(nf&1) + r
  int qabs = q0 + w * 16 + lr;
  f32x4 biasv[4];
  if (qt > 0) {
#pragma unroll
    for (int nf = 0; nf < 4; nf++)
#pragma unroll
      for (int r = 0; r < 4; r++)
        biasv[nf][r] = -slope2 * (float)(qabs - (32 * (nf >> 1) + 8 * lg + 4 * (nf & 1) + r));
  }

  // K-read: A-frag row for subtile nf = f(nf,lr); read swizzles (nf-independent)
  int kbase_row = ((lr >> 2) << 3) + (lr & 3);
  int SK = (lr & 3) | (((lr >> 2) & 1) << 2);
  int SV = (lr & 3) | (((lr >> 3) & 1) << 2);

  stage(0, 0);
  __syncthreads();

  for (int tt = 0; tt < S_LEN / 64; tt++) {
    int cur = tt & 1;
    if (tt + 1 < S_LEN / 64) stage(tt + 1, cur ^ 1);
    bool diag = (tt == qt);

    // S^T: rows = permuted kv, cols = q; C-in = alibi bias
    f32x4 sc[4];
    __builtin_amdgcn_s_setprio(1);
#pragma unroll
    for (int nf = 0; nf < 4; nf++) {
      int kvr = kbase_row + ((nf & 1) << 2) + ((nf >> 1) << 5);
      f32x4 a = diag ? f32x4{0.f, 0.f, 0.f, 0.f} : biasv[nf];
#pragma unroll
      for (int ks = 0; ks < 2; ks++) {
        bf16x8 kf = *(const bf16x8*)(&Ks[cur][kvr * 64 + (((ks * 4 + lg) ^ SK) << 3)]);
        a = __builtin_amdgcn_mfma_f32_16x16x32_bf16(kf, qf[ks], a, 0, 0, 0);
      }
      sc[nf] = a;
    }
    __builtin_amdgcn_s_setprio(0);

    if (diag) {
      int qq = w * 16 + lr;  // q0 == tt*64 cancels
#pragma unroll
      for (int nf = 0; nf < 4; nf++)
#pragma unroll
        for (int r = 0; r < 4; r++) {
          int kvloc = 32 * (nf >> 1) + 8 * lg + 4 * (nf & 1) + r;
          sc[nf][r] -= slope2 * fabsf((float)(qq - kvloc));
          biasv[nf][r] = -slope2 * (float)(64 + kvloc - qq);  // seed next tile (above diag)
        }
    }

    // row max: in-thread tree + 2 cross-lg shuffles
    float mx = -INFINITY;
#pragma unroll
    for (int nf = 0; nf < 4; nf++)
#pragma unroll
      for (int r = 0; r < 4; r++) mx = fmaxf(mx, sc[nf][r]);
    mx = fmaxf(mx, __shfl_xor(mx, 16, 64));
    mx = fmaxf(mx, __shfl_xor(mx, 32, 64));

    // dead-tile skip: every P would be < 2^-25 of the running max -> no contribution
    if (!__all(mx < mrow - 25.0f)) {
      if (__any(mx > mrow)) {
        float mn = fmaxf(mrow, mx);
        float scl = exp2f(mrow - mn);  // 0 on first tile
        mrow = mn;
        lden *= scl;
        float so[4];
#pragma unroll
        for (int r = 0; r < 4; r++) so[r] = __shfl(scl, lg * 4 + r, 64);
#pragma unroll
        for (int nf = 0; nf < 4; nf++)
#pragma unroll
          for (int r = 0; r < 4; r++) ao[nf][r] *= so[r];
      }

      // P = exp2(S - m); sum; bf16 pack (all lane-local)
      float su = 0.f;
#pragma unroll
      for (int nf = 0; nf < 4; nf++)
#pragma unroll
        for (int r = 0; r < 4; r++) {
          float p = exp2f(sc[nf][r] - mrow);
          sc[nf][r] = p;
          su += p;
        }
      su += __shfl_xor(su, 16, 64);
      su += __shfl_xor(su, 32, 64);
      lden += su;

      bf16x8 pf[2];
#pragma unroll
      for (int ks = 0; ks < 2; ks++)
#pragma unroll
        for (int j = 0; j < 8; j++)
          pf[ks][j] = (__bf16)sc[2 * ks + (j >> 2)][j & 3];

      // O += P @ V
      __builtin_amdgcn_s_setprio(1);
#pragma unroll
      for (int nf = 0; nf < 4; nf++) {
        int d = nf * 16 + lr;
#pragma unroll
        for (int ks = 0; ks < 2; ks++) {
          bf16x8 vf = *(const bf16x8*)(&VTs[cur][d * 64 + (((ks * 4 + lg) ^ SV) << 3)]);
          ao[nf] = __builtin_amdgcn_mfma_f32_16x16x32_bf16(pf[ks], vf, ao[nf], 0, 0, 0);
        }
      }
      __builtin_amdgcn_s_setprio(0);
    }

    // bias ladder update (next tile), skip if next is diagonal (seeded there)
    int next = tt + 1;
    if (!diag && next != qt) {
      float dd = (next < qt) ? s64v : -s64v;
#pragma unroll
      for (int nf = 0; nf < 4; nf++)
#pragma unroll
        for (int r = 0; r < 4; r++) biasv[nf][r] += dd;
    }
    __syncthreads();  // drains vmcnt (next-tile stage); safe to reuse buffers
  }

  // epilogue: O[q=lg*4+r][d=nf*16+lr] / lden(q-row)
  float inv[4];
#pragma unroll
  for (int r = 0; r < 4; r++) inv[r] = 1.0f / __shfl(lden, lg * 4 + r, 64);
  int token_base = (bh >> 4) * S_LEN + q0 + w * 16;
#pragma unroll
  for (int nf = 0; nf < 4; nf++) {
#pragma unroll
    for (int r = 0; r < 4; r++) {
      int token = token_base + lg * 4 + r;
      int d = nf * 16 + lr;
      attn_out[(size_t)token * HIDN + h * HDIM + d] = f2bf(ao[nf][r] * inv[r]);
    }
  }
}

// ---------------- launcher ----------------
extern "C" void kernel_launch(void* const* d_in, const int* in_sizes, int n_in,
                              void* d_out, int out_size, void* d_ws, size_t ws_size,
                              hipStream_t stream) {
  const float* x   = (const float*)d_in[0];
  const float* n1w = (const float*)d_in[1];
  const float* Wq  = (const float*)d_in[2];
  const float* bq  = (const float*)d_in[3];
  const float* Wk  = (const float*)d_in[4];
  const float* bk  = (const float*)d_in[5];
  const float* Wv  = (const float*)d_in[6];
  const float* Wo  = (const float*)d_in[7];
  const float* n2w = (const float*)d_in[8];
  const float* W1  = (const float*)d_in[9];
  const float* b1  = (const float*)d_in[10];
  const float* W2  = (const float*)d_in[11];
  const float* b2  = (const float*)d_in[12];
  float* out = (float*)d_out;

  char* ws = (char*)d_ws;
  ushort* xn     = (ushort*)(ws + 0);          // 8388608
  ushort* wqkvT  = (ushort*)(ws + 8388608);    // 6291456
  ushort* woT    = (ushort*)(ws + 14680064);   // 2097152
  ushort* w1T    = (ushort*)(ws + 16777216);   // 8388608
  ushort* w2T    = (ushort*)(ws + 25165824);   // 8388608
  ushort* qbuf   = (ushort*)(ws + 33566720);   // 8388608
  ushort* kbuf   = (ushort*)(ws + 41955328);   // 8388608
  ushort* vtbuf  = (ushort*)(ws + 50343936);   // 8388608 (V^T: [bh][d][s])
  ushort* attnb  = (ushort*)(ws + 58732544);   // 8388608
  float*  x2     = (float*)(ws + 67121152);    // 16777216
  ushort* xn2    = (ushort*)(ws + 83898368);   // 8388608
  ushort* hbuf   = qbuf;  // alias: q/k/vT/attn (33554432 B) dead before FFN needs h

  dim3 blk(256);

  // all weights -> bf16 transposed [N][K], one kernel
  convert_all<<<dim3(12288), blk, 0, stream>>>(Wq, Wk, Wv, Wo, W1, W2,
                                               wqkvT, woT, w1T, w2T);
  // norm1
  rmsnorm_kernel<<<NTOK, blk, 0, stream>>>(x, n1w, xn);
  // QKV (V written transposed; bias = bq, resid slot = bk)
  gemm_bt<0, 128><<<dim3(32, 24), blk, 0, stream>>>(xn, wqkvT, NTOK, 3 * HIDN, HIDN,
                                                    bq, bk, nullptr, nullptr,
                                                    qbuf, kbuf, vtbuf);
  // attention
  attn_kernel<<<dim3(32 * 32), blk, 0, stream>>>(qbuf, kbuf, vtbuf, attnb);
  // Wo + residual
  gemm_bt<1, 64><<<dim3(64, 8), blk, 0, stream>>>(attnb, woT, NTOK, HIDN, HIDN,
                                                  nullptr, x, x2, nullptr,
                                                  nullptr, nullptr, nullptr);
  // norm2
  rmsnorm_kernel<<<NTOK, blk, 0, stream>>>(x2, n2w, xn2);
  // FFN1 + GELU
  gemm_bt<2, 128><<<dim3(32, 32), blk, 0, stream>>>(xn2, w1T, NTOK, DFFN, HIDN,
                                                    b1, nullptr, nullptr, hbuf,
                                                    nullptr, nullptr, nullptr);
  // FFN2 split-K=2: seed out = x2 + 0.5*b2, then atomic-accumulate 0.5*acc
  out_init<<<dim3(4096), blk, 0, stream>>>(x2, b2, out);
  gemm_bt<5, 64><<<dim3(64, 8, 2), blk, 0, stream>>>(hbuf, w2T, NTOK, HIDN, DFFN,
                                                     nullptr, nullptr, out, nullptr,
                                                     nullptr, nullptr, nullptr);
}

// Round 10
// 372.233 us; speedup vs baseline: 1.0595x; 1.0595x over previous
//
#include <hip/hip_runtime.h>
#include <hip/hip_bf16.h>
#include <math.h>

// ---- problem constants ----
#define S_LEN   2048
#define HIDN    1024
#define NHEADS  16
#define HDIM    64
#define NTOK    4096   // B*S
#define DFFN    4096

#define LOG2E 1.44269504088896f

typedef __attribute__((ext_vector_type(8))) __bf16 bf16x8;
typedef __attribute__((ext_vector_type(4))) float  f32x4;

static __device__ __forceinline__ ushort f2bf(float f) {
  union { float f; unsigned u; } v; v.f = f;
  unsigned u = v.u;
  unsigned r = (u + 0x7fffu + ((u >> 16) & 1u)) >> 16;  // RNE
  return (ushort)r;
}

// async global->LDS, 16B per lane; LDS dest = wave-uniform base + lane*16 (HW-appended)
#define GLOAD16(gp, lp)                                                              \
  __builtin_amdgcn_global_load_lds((const __attribute__((address_space(1))) void*)(gp), \
                                   (__attribute__((address_space(3))) void*)(lp), 16, 0, 0)

// ---------------- fused transpose-convert: all weights fp32 [K][N] -> bf16 [N][K] ----------------
__global__ __launch_bounds__(256) void convert_all(const float* __restrict__ Wq,
                                                   const float* __restrict__ Wk,
                                                   const float* __restrict__ Wv,
                                                   const float* __restrict__ Wo,
                                                   const float* __restrict__ W1,
                                                   const float* __restrict__ W2,
                                                   ushort* __restrict__ wqkvT,
                                                   ushort* __restrict__ woT,
                                                   ushort* __restrict__ w1T,
                                                   ushort* __restrict__ w2T) {
  __shared__ float tile[32][33];
  int id = blockIdx.x;
  const float* W; ushort* WT; int K, N, tl;
  if (id < 3072) {                 // Wq/Wk/Wv: 1024x1024 each
    int i = id >> 10; tl = id & 1023;
    W = (i == 0) ? Wq : (i == 1) ? Wk : Wv;
    WT = wqkvT + i * 1024 * 1024; K = 1024; N = 1024;
  } else if (id < 4096) { tl = id - 3072; W = Wo; WT = woT; K = 1024; N = 1024; }
  else if (id < 8192)   { tl = id - 4096; W = W1; WT = w1T; K = 1024; N = 4096; }
  else                  { tl = id - 8192; W = W2; WT = w2T; K = 4096; N = 1024; }
  int ntn = N >> 5;
  int n0 = (tl % ntn) * 32, k0 = (tl / ntn) * 32;
  int tx = threadIdx.x & 31, ty = threadIdx.x >> 5;  // ty 0..7
#pragma unroll
  for (int i = 0; i < 4; i++)
    tile[ty + i * 8][tx] = W[(size_t)(k0 + ty + i * 8) * N + n0 + tx];
  __syncthreads();
#pragma unroll
  for (int i = 0; i < 4; i++)
    WT[(size_t)(n0 + ty + i * 8) * K + k0 + tx] = f2bf(tile[tx][ty + i * 8]);
}

// ---------------- RMSNorm: fp32 row -> bf16 row ----------------
__global__ __launch_bounds__(256) void rmsnorm_kernel(const float* __restrict__ x,
                                                      const float* __restrict__ w,
                                                      ushort* __restrict__ out) {
  int row = blockIdx.x, t = threadIdx.x;
  const float4* x4 = (const float4*)(x + (size_t)row * HIDN);
  float4 v = x4[t];
  float ss = v.x * v.x + v.y * v.y + v.z * v.z + v.w * v.w;
#pragma unroll
  for (int m = 32; m; m >>= 1) ss += __shfl_xor(ss, m, 64);
  __shared__ float wsum[4];
  if ((t & 63) == 0) wsum[t >> 6] = ss;
  __syncthreads();
  float tot = wsum[0] + wsum[1] + wsum[2] + wsum[3];
  float rs = rsqrtf(tot * (1.0f / HIDN) + 1e-6f);
  const float4* w4 = (const float4*)w;
  float4 wv = w4[t];
  ushort4 o;
  o.x = f2bf(v.x * rs * wv.x);
  o.y = f2bf(v.y * rs * wv.y);
  o.z = f2bf(v.z * rs * wv.z);
  o.w = f2bf(v.w * rs * wv.w);
  *(ushort4*)(out + (size_t)row * HIDN + t * 4) = o;
}

// ---------------- bf16 MFMA GEMM, A[M][K] x B^T[N][K], TMx128 tile, BK=64 ----------------
// XCD-aware block swizzle (all grids have nwg % 8 == 0).
// EPI: 0 = QKV scatter (bias = bq, resid = bk; q*0.125*log2e, V transposed),
//      1 = Wo (+resid -> fp32), 2 = W1 (+bias, gelu -> bf16), 3 = W2 (resid + 0.5*(acc+bias))
template <int EPI, int TM>
__global__ __launch_bounds__(256, 3) void gemm_bt(const ushort* __restrict__ A,
                                                  const ushort* __restrict__ B,
                                                  int M, int N, int K,
                                                  const float* __restrict__ bias,
                                                  const float* __restrict__ resid,
                                                  float* __restrict__ outf,
                                                  ushort* __restrict__ outb,
                                                  ushort* __restrict__ qb,
                                                  ushort* __restrict__ kb,
                                                  ushort* __restrict__ vb) {
  constexpr int NF = (TM == 128) ? 4 : 2;    // 16-col fragments per wave
  __shared__ __align__(16) ushort As[TM * 64];
  __shared__ __align__(16) ushort Bs[128 * 64];
  int t = threadIdx.x;
  int w = t >> 6, l = t & 63;
  int wmr = (TM == 128) ? (w >> 1) * 64 : 0;        // wave row base
  int wnc = (TM == 128) ? (w & 1) * 64 : w * 32;    // wave col base
  int lr = l & 15, lg = l >> 4;

  // XCD swizzle
  int nwg = gridDim.x * gridDim.y;
  int bid = blockIdx.y * gridDim.x + blockIdx.x;
  int swz = (bid & 7) * (nwg >> 3) + (bid >> 3);
  int bx = swz % gridDim.x, by = swz / gridDim.x;
  int m0 = bx * TM, n0 = by * 128;

  // staging: each GLOAD16 covers 8 rows x 64 cols; lane l -> row l>>3,
  // LDS granule l&7, sourced from global granule (l&7)^(l>>3)  [swizzle]
  int srl = l >> 3;
  int sg  = ((l & 7) ^ srl) * 8;
  const ushort* Ag = A + (size_t)(m0 + w * (TM / 4) + srl) * K + sg;
  const ushort* Bg = B + (size_t)(n0 + w * 32 + srl) * K + sg;
  ushort* Asw = &As[(w * (TM / 4)) * 64];
  ushort* Bsw = &Bs[(w * 32) * 64];

  f32x4 acc[4][NF] = {};

  for (int k0 = 0; k0 < K; k0 += 64) {
#pragma unroll
    for (int c = 0; c < TM / 32; c++)
      GLOAD16(Ag + (size_t)(8 * c) * K + k0, Asw + (8 * c) * 64);
#pragma unroll
    for (int c = 0; c < 4; c++)
      GLOAD16(Bg + (size_t)(8 * c) * K + k0, Bsw + (8 * c) * 64);
    __syncthreads();  // drains vmcnt -> LDS tiles ready

    bf16x8 af[4][2], bfr[NF][2];
#pragma unroll
    for (int mf = 0; mf < 4; mf++)
#pragma unroll
      for (int ks = 0; ks < 2; ks++)
        af[mf][ks] = *(const bf16x8*)(&As[(wmr + mf * 16 + lr) * 64 +
                                          (((ks * 4 + lg) ^ (lr & 7)) << 3)]);
#pragma unroll
    for (int nf = 0; nf < NF; nf++)
#pragma unroll
      for (int ks = 0; ks < 2; ks++)
        bfr[nf][ks] = *(const bf16x8*)(&Bs[(wnc + nf * 16 + lr) * 64 +
                                           (((ks * 4 + lg) ^ (lr & 7)) << 3)]);
#pragma unroll
    for (int mf = 0; mf < 4; mf++)
#pragma unroll
      for (int nf = 0; nf < NF; nf++) {
        acc[mf][nf] = __builtin_amdgcn_mfma_f32_16x16x32_bf16(af[mf][0], bfr[nf][0], acc[mf][nf], 0, 0, 0);
        acc[mf][nf] = __builtin_amdgcn_mfma_f32_16x16x32_bf16(af[mf][1], bfr[nf][1], acc[mf][nf], 0, 0, 0);
      }
    __syncthreads();  // all reads done before next overwrite
  }

  // epilogue: C row = (l>>4)*4 + r, col = l&15  [verified C/D layout]
  int lg4 = lg * 4;
  if constexpr (EPI == 0) {
#pragma unroll
    for (int mf = 0; mf < 4; mf++) {
      int row0 = m0 + wmr + mf * 16 + lg4;
      int bb = row0 >> 11, ss0 = row0 & 2047;
#pragma unroll
      for (int nf = 0; nf < NF; nf++) {
        int col = n0 + wnc + nf * 16 + lr;
        int which = col >> 10, nn = col & 1023;
        int hh = nn >> 6, dd = nn & 63;
        float bcol = (which == 0) ? bias[nn] : (which == 1) ? resid[nn] : 0.0f;
        if (which == 2) {
          // V transposed: vT[bh][d][s]; 4 consecutive ss pack into ushort4
          ushort4 o;
          o.x = f2bf(acc[mf][nf][0]);
          o.y = f2bf(acc[mf][nf][1]);
          o.z = f2bf(acc[mf][nf][2]);
          o.w = f2bf(acc[mf][nf][3]);
          *(ushort4*)(vb + ((size_t)(bb * NHEADS + hh) * HDIM + dd) * S_LEN + ss0) = o;
        } else {
#pragma unroll
          for (int r = 0; r < 4; r++) {
            float v = acc[mf][nf][r] + bcol;
            size_t idx = ((size_t)(bb * NHEADS + hh) * S_LEN + ss0 + r) * HDIM + dd;
            if (which == 0) qb[idx] = f2bf(v * (0.125f * LOG2E));
            else kb[idx] = f2bf(v);
          }
        }
      }
    }
  } else {
#pragma unroll
    for (int mf = 0; mf < 4; mf++) {
#pragma unroll
      for (int nf = 0; nf < NF; nf++) {
#pragma unroll
        for (int r = 0; r < 4; r++) {
          int row = m0 + wmr + mf * 16 + lg4 + r;
          int col = n0 + wnc + nf * 16 + lr;
          float v = acc[mf][nf][r];
          if constexpr (EPI == 1) {
            outf[(size_t)row * HIDN + col] = resid[(size_t)row * HIDN + col] + v;
          } else if constexpr (EPI == 2) {
            float tv = v + bias[col];
            float gl = 0.5f * tv * (1.0f + erff(tv * 0.70710678118f));
            outb[(size_t)row * DFFN + col] = f2bf(gl);
          } else {
            outf[(size_t)row * HIDN + col] =
                resid[(size_t)row * HIDN + col] + 0.5f * (v + bias[col]);
          }
        }
      }
    }
  }
}

// ---------------- flash attention with ALiBi — lane-local P, outward tile order ----------------
// Diagonal-first, alternate-outward tile order: after the diag, mrow is near-final, so
// distant tiles on BOTH sides satisfy the exact dead-tile test (all P < 2^-25 of max)
// and skip softmax+PV. Tile sequence is wave-uniform scalar state (lo/hi), no arrays.
// ALiBi bias computed per tile directly into the MFMA C-operand.
__global__ __launch_bounds__(256, 4) void attn_kernel(const ushort* __restrict__ qb,
                                                      const ushort* __restrict__ kb,
                                                      const ushort* __restrict__ vt,
                                                      ushort* __restrict__ attn_out) {
  __shared__ __align__(16) ushort Ks[2][64 * 64];
  __shared__ __align__(16) ushort VTs[2][64 * 64];
  int t = threadIdx.x;
  int w = t >> 6, l = t & 63;
  int lr = l & 15, lg = l >> 4, g8 = lg * 8;

  // head-pair XCD mapping: v = xcd*128 + idx; qt = v&31; g = v>>5;
  // h = (g>>1 & 7) + 8*(g&1): each XCD gets head-pair {hp, hp+8} -> balanced skip load
  int bid = blockIdx.x;
  int v = (bid & 7) * 128 + (bid >> 3);
  int qt = v & 31;
  int g = v >> 5;
  int h = (g >> 1 & 7) + 8 * (g & 1);
  int bh = (g >> 4) * 16 + h;
  float slope2 = exp2f(-0.5f * (float)(h + 1)) * LOG2E;  // log2-domain alibi slope
  int q0 = qt * 64;
  const ushort* qp = qb + (size_t)bh * S_LEN * HDIM;
  const ushort* kp = kb + (size_t)bh * S_LEN * HDIM;
  const ushort* vp = vt + (size_t)bh * HDIM * S_LEN;

  // staging: chunk c covers rows w*16+8c..+7; source granule = (l&7) ^ S(row),
  // S(row) = (row&3) | ((row>>3)&1)<<2; row = w*16+8c+(l>>3) -> S = ((l>>3)&3) | (c<<2)
  int S0 = (l >> 3) & 3;
  size_t kof0 = (size_t)(w * 16 + (l >> 3)) * HDIM + (size_t)(((l & 7) ^ S0) * 8);
  size_t kof1 = (size_t)(w * 16 + 8 + (l >> 3)) * HDIM + (size_t)(((l & 7) ^ S0 ^ 4) * 8);
  size_t vof0 = (size_t)(w * 16 + (l >> 3)) * S_LEN + (size_t)(((l & 7) ^ S0) * 8);
  size_t vof1 = (size_t)(w * 16 + 8 + (l >> 3)) * S_LEN + (size_t)(((l & 7) ^ S0 ^ 4) * 8);

  auto stage = [&](int tile, int b) {
    const ushort* ks_ = kp + (size_t)tile * 64 * HDIM;
    const ushort* vs_ = vp + tile * 64;
    GLOAD16(ks_ + kof0, &Ks[b][(w * 16) * 64]);
    GLOAD16(ks_ + kof1, &Ks[b][(w * 16 + 8) * 64]);
    GLOAD16(vs_ + vof0, &VTs[b][(w * 16) * 64]);
    GLOAD16(vs_ + vof1, &VTs[b][(w * 16 + 8) * 64]);
  };

  // Q as B-frag: B[col=lr][k]
  bf16x8 qf[2];
#pragma unroll
  for (int ks = 0; ks < 2; ks++)
    qf[ks] = *(const bf16x8*)(qp + (size_t)(q0 + w * 16 + lr) * HDIM + ks * 32 + g8);

  f32x4 ao[4] = {};                 // O[q = lg*4+r][d = nf*16+lr]
  float mrow = -INFINITY, lden = 0.f;  // per-thread: one q-row (q = w*16+lr)

  // lane-local kv coords of sc[nf][r]: kvloc = 32*(nf>>1) + 8*lg + 4*(nf&1) + r
  float qabs_f = (float)(q0 + w * 16 + lr);
  float kvlocf[4][4];
#pragma unroll
  for (int nf = 0; nf < 4; nf++)
#pragma unroll
    for (int r = 0; r < 4; r++)
      kvlocf[nf][r] = (float)(32 * (nf >> 1) + 8 * lg + 4 * (nf & 1) + r);

  // K-read: A-frag row for subtile nf = f(nf,lr); read swizzles (nf-independent)
  int kbase_row = ((lr >> 2) << 3) + (lr & 3);
  int SK = (lr & 3) | (((lr >> 2) & 1) << 2);
  int SV = (lr & 3) | (((lr >> 3) & 1) << 2);

  // outward tile sequence state (all wave-uniform scalars)
  int lo = qt, hi = qt;
  auto nexttile = [&]() {
    bool canHi = (hi < 31), canLo = (lo > 0);
    if (canHi && (!canLo || (hi - qt) <= (qt - lo))) return ++hi;
    return --lo;
  };

  int t_cur = qt;
  int t_nxt = nexttile();
  stage(t_cur, 0);
  __syncthreads();
  int cur = 0;

  for (int it = 0; it < S_LEN / 64; it++) {
    if (it + 1 < S_LEN / 64) stage(t_nxt, cur ^ 1);
    bool diag = (t_cur == qt);
    float d0f = qabs_f - (float)(t_cur * 64);   // q - tile_base

    // S^T: rows = permuted kv, cols = q; C-in = alibi bias (0 on diag, exact |.| after)
    f32x4 sc[4];
    __builtin_amdgcn_s_setprio(1);
#pragma unroll
    for (int nf = 0; nf < 4; nf++) {
      int kvr = kbase_row + ((nf & 1) << 2) + ((nf >> 1) << 5);
      f32x4 a;
      if (diag) {
        a = f32x4{0.f, 0.f, 0.f, 0.f};
      } else {
#pragma unroll
        for (int r = 0; r < 4; r++) a[r] = -slope2 * fabsf(d0f - kvlocf[nf][r]);
      }
#pragma unroll
      for (int ks = 0; ks < 2; ks++) {
        bf16x8 kf = *(const bf16x8*)(&Ks[cur][kvr * 64 + (((ks * 4 + lg) ^ SK) << 3)]);
        a = __builtin_amdgcn_mfma_f32_16x16x32_bf16(kf, qf[ks], a, 0, 0, 0);
      }
      sc[nf] = a;
    }
    __builtin_amdgcn_s_setprio(0);

    if (diag) {
#pragma unroll
      for (int nf = 0; nf < 4; nf++)
#pragma unroll
        for (int r = 0; r < 4; r++)
          sc[nf][r] -= slope2 * fabsf(d0f - kvlocf[nf][r]);
    }

    // row max: in-thread tree + 2 cross-lg shuffles
    float mx = -INFINITY;
#pragma unroll
    for (int nf = 0; nf < 4; nf++)
#pragma unroll
      for (int r = 0; r < 4; r++) mx = fmaxf(mx, sc[nf][r]);
    mx = fmaxf(mx, __shfl_xor(mx, 16, 64));
    mx = fmaxf(mx, __shfl_xor(mx, 32, 64));

    // dead-tile skip: every P would be < 2^-25 of the running max -> no contribution
    if (!__all(mx < mrow - 25.0f)) {
      if (__any(mx > mrow)) {
        float mn = fmaxf(mrow, mx);
        float scl = exp2f(mrow - mn);  // 0 on first (diag) tile
        mrow = mn;
        lden *= scl;
        float so[4];
#pragma unroll
        for (int r = 0; r < 4; r++) so[r] = __shfl(scl, lg * 4 + r, 64);
#pragma unroll
        for (int nf = 0; nf < 4; nf++)
#pragma unroll
          for (int r = 0; r < 4; r++) ao[nf][r] *= so[r];
      }

      // P = exp2(S - m); sum; bf16 pack (all lane-local)
      float su = 0.f;
#pragma unroll
      for (int nf = 0; nf < 4; nf++)
#pragma unroll
        for (int r = 0; r < 4; r++) {
          float p = exp2f(sc[nf][r] - mrow);
          sc[nf][r] = p;
          su += p;
        }
      su += __shfl_xor(su, 16, 64);
      su += __shfl_xor(su, 32, 64);
      lden += su;

      bf16x8 pf[2];
#pragma unroll
      for (int ks = 0; ks < 2; ks++)
#pragma unroll
        for (int j = 0; j < 8; j++)
          pf[ks][j] = (__bf16)sc[2 * ks + (j >> 2)][j & 3];

      // O += P @ V
      __builtin_amdgcn_s_setprio(1);
#pragma unroll
      for (int nf = 0; nf < 4; nf++) {
        int d = nf * 16 + lr;
#pragma unroll
        for (int ks = 0; ks < 2; ks++) {
          bf16x8 vf = *(const bf16x8*)(&VTs[cur][d * 64 + (((ks * 4 + lg) ^ SV) << 3)]);
          ao[nf] = __builtin_amdgcn_mfma_f32_16x16x32_bf16(pf[ks], vf, ao[nf], 0, 0, 0);
        }
      }
      __builtin_amdgcn_s_setprio(0);
    }

    __syncthreads();  // drains vmcnt (next-tile stage); safe to reuse buffers
    t_cur = t_nxt;
    if (it + 2 < S_LEN / 64) t_nxt = nexttile();
    cur ^= 1;
  }

  // epilogue: O[q=lg*4+r][d=nf*16+lr] / lden(q-row)
  float inv[4];
#pragma unroll
  for (int r = 0; r < 4; r++) inv[r] = 1.0f / __shfl(lden, lg * 4 + r, 64);
  int token_base = (bh >> 4) * S_LEN + q0 + w * 16;
#pragma unroll
  for (int nf = 0; nf < 4; nf++) {
#pragma unroll
    for (int r = 0; r < 4; r++) {
      int token = token_base + lg * 4 + r;
      int d = nf * 16 + lr;
      attn_out[(size_t)token * HIDN + h * HDIM + d] = f2bf(ao[nf][r] * inv[r]);
    }
  }
}

// ---------------- launcher ----------------
extern "C" void kernel_launch(void* const* d_in, const int* in_sizes, int n_in,
                              void* d_out, int out_size, void* d_ws, size_t ws_size,
                              hipStream_t stream) {
  const float* x   = (const float*)d_in[0];
  const float* n1w = (const float*)d_in[1];
  const float* Wq  = (const float*)d_in[2];
  const float* bq  = (const float*)d_in[3];
  const float* Wk  = (const float*)d_in[4];
  const float* bk  = (const float*)d_in[5];
  const float* Wv  = (const float*)d_in[6];
  const float* Wo  = (const float*)d_in[7];
  const float* n2w = (const float*)d_in[8];
  const float* W1  = (const float*)d_in[9];
  const float* b1  = (const float*)d_in[10];
  const float* W2  = (const float*)d_in[11];
  const float* b2  = (const float*)d_in[12];
  float* out = (float*)d_out;

  char* ws = (char*)d_ws;
  ushort* xn     = (ushort*)(ws + 0);          // 8388608
  ushort* wqkvT  = (ushort*)(ws + 8388608);    // 6291456
  ushort* woT    = (ushort*)(ws + 14680064);   // 2097152
  ushort* w1T    = (ushort*)(ws + 16777216);   // 8388608
  ushort* w2T    = (ushort*)(ws + 25165824);   // 8388608
  ushort* qbuf   = (ushort*)(ws + 33566720);   // 8388608
  ushort* kbuf   = (ushort*)(ws + 41955328);   // 8388608
  ushort* vtbuf  = (ushort*)(ws + 50343936);   // 8388608 (V^T: [bh][d][s])
  ushort* attnb  = (ushort*)(ws + 58732544);   // 8388608
  float*  x2     = (float*)(ws + 67121152);    // 16777216
  ushort* xn2    = (ushort*)(ws + 83898368);   // 8388608
  ushort* hbuf   = qbuf;  // alias: q/k/vT/attn (33554432 B) dead before FFN needs h

  dim3 blk(256);

  // all weights -> bf16 transposed [N][K], one kernel
  convert_all<<<dim3(12288), blk, 0, stream>>>(Wq, Wk, Wv, Wo, W1, W2,
                                               wqkvT, woT, w1T, w2T);
  // norm1
  rmsnorm_kernel<<<NTOK, blk, 0, stream>>>(x, n1w, xn);
  // QKV (V written transposed; bias = bq, resid slot = bk)
  gemm_bt<0, 128><<<dim3(32, 24), blk, 0, stream>>>(xn, wqkvT, NTOK, 3 * HIDN, HIDN,
                                                    bq, bk, nullptr, nullptr,
                                                    qbuf, kbuf, vtbuf);
  // attention
  attn_kernel<<<dim3(32 * 32), blk, 0, stream>>>(qbuf, kbuf, vtbuf, attnb);
  // Wo + residual
  gemm_bt<1, 64><<<dim3(64, 8), blk, 0, stream>>>(attnb, woT, NTOK, HIDN, HIDN,
                                                  nullptr, x, x2, nullptr,
                                                  nullptr, nullptr, nullptr);
  // norm2
  rmsnorm_kernel<<<NTOK, blk, 0, stream>>>(x2, n2w, xn2);
  // FFN1 + GELU
  gemm_bt<2, 128><<<dim3(32, 32), blk, 0, stream>>>(xn2, w1T, NTOK, DFFN, HIDN,
                                                    b1, nullptr, nullptr, hbuf,
                                                    nullptr, nullptr, nullptr);
  // FFN2 + scaled residual -> out (single pass, reverted from split-K)
  gemm_bt<3, 64><<<dim3(64, 8), blk, 0, stream>>>(hbuf, w2T, NTOK, HIDN, DFFN,
                                                  b2, x2, out, nullptr,
                                                  nullptr, nullptr, nullptr);
}